// Round 5
// baseline (279.917 us; speedup 1.0000x reference)
//
#include <hip/hip_runtime.h>
#include <hip/hip_bf16.h>
#include <stdint.h>

typedef __bf16 bf16x8 __attribute__((ext_vector_type(8)));
typedef float  f32x4  __attribute__((ext_vector_type(4)));
typedef unsigned short ushort8v __attribute__((ext_vector_type(8)));

__device__ __forceinline__ unsigned short f2bf(float f) {
  unsigned int u = __float_as_uint(f);
  u += 0x7FFF + ((u >> 16) & 1);          // round-to-nearest-even
  return (unsigned short)(u >> 16);
}

#define GLOAD_LDS(gptr, ldsptr)                                                     \
  __builtin_amdgcn_global_load_lds(                                                 \
      (const __attribute__((address_space(1))) unsigned int*)(gptr),                \
      (__attribute__((address_space(3))) unsigned int*)(ldsptr), 16, 0, 0)

#define BM 128
#define BN 128
#define BK 32

// ============ 128x128 3-buf GEMM: C = A[M,K] * B[N,K]^T (bf16 in) ============
// mode 0: C bf16 [M,N]; mode 1: C bf16 transposed-per-batch (vhT); mode 2: fp32*scale
// mode 3: merged projections (z<2 -> mode 0, z==2 -> mode 1)
// tilemap 0: m204 XCD chunk swizzle, mt = wg/ntiles (uniform-work grids)
// tilemap 1: triangular decode of blockIdx.x -> (mt,nt), nt<=mt (causal S; RR-balanced)
__global__ __launch_bounds__(256, 3) void gemm_bt(
    const unsigned short* __restrict__ A,
    const unsigned short* __restrict__ B,
    void* __restrict__ C,
    int M, int N, int K, int ntiles,
    long sAz, long sBz, long sCz,
    int mode, int tilemap, float scale)
{
  int mt, nt;
  const int orig = blockIdx.x;
  if (tilemap == 0) {
    const int nwg = gridDim.x;
    const int qq = nwg >> 3, rr = nwg & 7, xc = orig & 7, oo = orig >> 3;
    const int wg = (xc < rr ? xc * (qq + 1) : rr * (qq + 1) + (xc - rr) * qq) + oo;
    mt = wg / ntiles; nt = wg % ntiles;
  } else {
    mt = (int)((sqrtf(8.f * orig + 1.f) - 1.f) * 0.5f);
    int base = mt * (mt + 1) / 2;
    if (orig < base) { mt--; base = mt * (mt + 1) / 2; }
    else if (orig >= base + mt + 1) { mt++; base = mt * (mt + 1) / 2; }
    nt = orig - base;
  }
  const int z = blockIdx.y;
  const int emode = (mode == 3) ? (z == 2 ? 1 : 0) : mode;

  A += sAz * (long)z;
  B += sBz * (long)z;

  __shared__ __align__(16) unsigned short As[3][BM * BK];
  __shared__ __align__(16) unsigned short Bs[3][BN * BK];

  const int tid  = threadIdx.x;
  const int wave = tid >> 6;
  const int lane = tid & 63;
  const int wr = wave >> 1, wc = wave & 1;

  f32x4 acc[4][4];
#pragma unroll
  for (int i = 0; i < 4; ++i)
#pragma unroll
    for (int j = 0; j < 4; ++j) acc[i][j] = (f32x4){0.f, 0.f, 0.f, 0.f};

  const int kiters = K / BK;

  // staging: XOR-swizzled global source, linear LDS dest (rule 21)
  const int r0 = tid >> 2, s0 = tid & 3;
  const int c0 = ((s0 ^ ((r0 >> 1) & 3)) << 3);
  const int r1 = r0 + 64;
  const int c1 = ((s0 ^ ((r1 >> 1) & 3)) << 3);
  const long aoff0 = (long)(mt * BM + r0) * K + c0;
  const long aoff1 = (long)(mt * BM + r1) * K + c1;
  const long boff0 = (long)(nt * BN + r0) * K + c0;
  const long boff1 = (long)(nt * BN + r1) * K + c1;
  const unsigned ldsw = wave * 1024;

#define STAGE(bi, k0)                                                     \
  do {                                                                    \
    GLOAD_LDS(A + aoff0 + (k0), (char*)&As[bi][0]    + ldsw);             \
    GLOAD_LDS(A + aoff1 + (k0), (char*)&As[bi][2048] + ldsw);             \
    GLOAD_LDS(B + boff0 + (k0), (char*)&Bs[bi][0]    + ldsw);             \
    GLOAD_LDS(B + boff1 + (k0), (char*)&Bs[bi][2048] + ldsw);             \
  } while (0)

  STAGE(0, 0);
  if (kiters > 1) STAGE(1, BK);

  int cur = 0;
  for (int kt = 0; kt < kiters; ++kt) {
    const int rem = kiters - 1 - kt;
    if (rem >= 2) {
      int sb = cur + 2; if (sb >= 3) sb -= 3;
      STAGE(sb, (kt + 2) * BK);
      asm volatile("s_waitcnt vmcnt(8)" ::: "memory");
    } else if (rem == 1) {
      asm volatile("s_waitcnt vmcnt(4)" ::: "memory");
    } else {
      asm volatile("s_waitcnt vmcnt(0)" ::: "memory");
    }
    __builtin_amdgcn_s_barrier();
    asm volatile("" ::: "memory");

    bf16x8 af[4], bfr[4];
#pragma unroll
    for (int i = 0; i < 4; ++i) {
      const int ar = wr * 64 + i * 16 + (lane & 15);
      const int as = ((lane >> 4) ^ ((ar >> 1) & 3)) << 3;
      af[i] = *(const bf16x8*)&As[cur][ar * BK + as];
      const int br = wc * 64 + i * 16 + (lane & 15);
      const int bs = ((lane >> 4) ^ ((br >> 1) & 3)) << 3;
      bfr[i] = *(const bf16x8*)&Bs[cur][br * BK + bs];
    }
#pragma unroll
    for (int mi = 0; mi < 4; ++mi)
#pragma unroll
      for (int ni = 0; ni < 4; ++ni)
        acc[mi][ni] = __builtin_amdgcn_mfma_f32_16x16x32_bf16(af[mi], bfr[ni], acc[mi][ni], 0, 0, 0);

    asm volatile("" ::: "memory");
    __builtin_amdgcn_s_barrier();
    cur = (cur == 2) ? 0 : cur + 1;
  }
#undef STAGE

  const int rb = mt * BM + wr * 64;
  const int cb = nt * BN + wc * 64;

  if (emode == 0) {
    unsigned short* Cb = (unsigned short*)C + sCz * (long)z;
#pragma unroll
    for (int mi = 0; mi < 4; ++mi)
#pragma unroll
      for (int ni = 0; ni < 4; ++ni) {
        const int row0 = rb + mi * 16 + ((lane >> 4) << 2);
        const int col  = cb + ni * 16 + (lane & 15);
#pragma unroll
        for (int j = 0; j < 4; ++j)
          Cb[(long)(row0 + j) * N + col] = f2bf(acc[mi][ni][j]);
      }
  } else if (emode == 1) {
    unsigned short* Cb = (unsigned short*)C + sCz * (long)z;
#pragma unroll
    for (int mi = 0; mi < 4; ++mi)
#pragma unroll
      for (int ni = 0; ni < 4; ++ni) {
        const int row0 = rb + mi * 16 + ((lane >> 4) << 2);
        const int col  = cb + ni * 16 + (lane & 15);
#pragma unroll
        for (int j = 0; j < 4; ++j) {
          const int row = row0 + j;
          const int b = row >> 11, l = row & 2047;
          Cb[((long)b * N + col) * 2048 + l] = f2bf(acc[mi][ni][j]);
        }
      }
  } else {
    float* Cf = (float*)C + sCz * (long)z;
#pragma unroll
    for (int mi = 0; mi < 4; ++mi)
#pragma unroll
      for (int ni = 0; ni < 4; ++ni) {
        const int row0 = rb + mi * 16 + ((lane >> 4) << 2);
        const int col  = cb + ni * 16 + (lane & 15);
#pragma unroll
        for (int j = 0; j < 4; ++j)
          Cf[(long)(row0 + j) * N + col] = acc[mi][ni][j] * scale;
      }
  }
}

// ====== fused softmax+PV: Y = softmax(S) * vh, 128x128 tile, causal K-limit ======
// A staged from fp32 S with on-the-fly p = exp(s-m)*inv (+ causal mask), bf16 cvt,
// swizzled ds_write (both-sides). B (vhT) staged via gload_lds w/ pre-swizzled src.
// Tile map: mt = (orig&8) ? 15-(orig&7) : (orig&7)  -> XCD c gets mt {c,15-c} (balanced).
__global__ __launch_bounds__(256, 3) void pv_fused(
    const float* __restrict__ S, const float2* __restrict__ stats,
    const unsigned short* __restrict__ vhT, unsigned short* __restrict__ Y)
{
  const int orig = blockIdx.x;              // 0..127
  const int z = blockIdx.y;
  const int mt = (orig & 8) ? (15 - (orig & 7)) : (orig & 7);
  const int nt = orig >> 4;                 // 0..7
  const float* Sb = S + (long)z * (2048L * 2048);
  const float2* st = stats + (long)z * 2048;
  const unsigned short* Bb = vhT + (long)z * (1024L * 2048);
  unsigned short* Yb = Y + (long)z * (2048L * 1024);

  __shared__ __align__(16) unsigned short As[2][128 * 32];
  __shared__ __align__(16) unsigned short Bs[2][128 * 32];

  const int tid = threadIdx.x, wave = tid >> 6, lane = tid & 63;
  const int wr = wave >> 1, wc = wave & 1;

  f32x4 acc[4][4];
#pragma unroll
  for (int i = 0; i < 4; ++i)
#pragma unroll
    for (int j = 0; j < 4; ++j) acc[i][j] = (f32x4){0.f, 0.f, 0.f, 0.f};

  const int kiters = (mt + 1) * 4;          // K = (mt+1)*128, BK=32

  // A staging geometry: thread t covers row t>>1, cols (t&1)*16 .. +15
  const int arow = tid >> 1;                // 0..127
  const int q = mt * 128 + arow;            // global query row
  const float2 ms = st[q];                  // {rowmax, 1/sum}
  const float* srow = Sb + (long)q * 2048;
  const int acs = (tid & 1) * 2;            // first 16B slot (0 or 2)
  const int asw = (arow >> 1) & 3;          // row swizzle
  unsigned short* wp0a = &As[0][arow * 32 + (acs ^ asw) * 8];
  unsigned short* wp1a = &As[0][arow * 32 + ((acs + 1) ^ asw) * 8];
  unsigned short* wp0b = &As[1][arow * 32 + (acs ^ asw) * 8];
  unsigned short* wp1b = &As[1][arow * 32 + ((acs + 1) ^ asw) * 8];

  // B staging (gload_lds, pre-swizzled source)
  const int r0 = tid >> 2, s0 = tid & 3;
  const int bc0 = ((s0 ^ ((r0 >> 1) & 3)) << 3);
  const int r1 = r0 + 64;
  const int bc1 = ((s0 ^ ((r1 >> 1) & 3)) << 3);
  const long boff0 = (long)(nt * 128 + r0) * 2048 + bc0;
  const long boff1 = (long)(nt * 128 + r1) * 2048 + bc1;
  const unsigned ldsw = wave * 1024;

  float4 av0, av1, av2, av3;

#define ISSUE_A(k0) do { const float4* sp = (const float4*)(srow + (k0) + acs * 8); \
    av0 = sp[0]; av1 = sp[1]; av2 = sp[2]; av3 = sp[3]; } while (0)
#define ISSUE_B(bi, k0) do {                                              \
    GLOAD_LDS(Bb + boff0 + (k0), (char*)&Bs[bi][0]    + ldsw);            \
    GLOAD_LDS(Bb + boff1 + (k0), (char*)&Bs[bi][2048] + ldsw); } while (0)
#define EXPWRITE(sel, k0) do {                                            \
    float pv_[16] = {av0.x, av0.y, av0.z, av0.w, av1.x, av1.y, av1.z, av1.w, \
                     av2.x, av2.y, av2.z, av2.w, av3.x, av3.y, av3.z, av3.w}; \
    ushort8v h0_, h1_;                                                    \
    _Pragma("unroll")                                                     \
    for (int i_ = 0; i_ < 8; ++i_) {                                      \
      const int col_ = (k0) + acs * 8 + i_;                               \
      h0_[i_] = (col_ <= q) ? f2bf(__expf(pv_[i_] - ms.x) * ms.y) : (unsigned short)0; } \
    _Pragma("unroll")                                                     \
    for (int i_ = 0; i_ < 8; ++i_) {                                      \
      const int col_ = (k0) + acs * 8 + 8 + i_;                           \
      h1_[i_] = (col_ <= q) ? f2bf(__expf(pv_[8 + i_] - ms.x) * ms.y) : (unsigned short)0; } \
    if (sel) { *(ushort8v*)wp0b = h0_; *(ushort8v*)wp1b = h1_; }          \
    else     { *(ushort8v*)wp0a = h0_; *(ushort8v*)wp1a = h1_; }          \
  } while (0)

  // prologue: tile 0 into buffer 0
  ISSUE_A(0); ISSUE_B(0, 0);
  asm volatile("s_waitcnt vmcnt(0)" ::: "memory");
  EXPWRITE(0, 0);
  asm volatile("s_waitcnt lgkmcnt(0)" ::: "memory");
  __builtin_amdgcn_s_barrier();
  asm volatile("" ::: "memory");

  int cur = 0;
  for (int kt = 0; kt < kiters; ++kt) {
    const int k0n = (kt + 1) * 32;
    const bool more = (kt + 1 < kiters);
    if (more) { ISSUE_A(k0n); ISSUE_B(cur ^ 1, k0n); }

    bf16x8 af[4], bfr[4];
#pragma unroll
    for (int i = 0; i < 4; ++i) {
      const int ar = wr * 64 + i * 16 + (lane & 15);
      const int as = ((lane >> 4) ^ ((ar >> 1) & 3)) << 3;
      af[i] = *(const bf16x8*)&As[cur][ar * 32 + as];
      const int br = wc * 64 + i * 16 + (lane & 15);
      const int bs = ((lane >> 4) ^ ((br >> 1) & 3)) << 3;
      bfr[i] = *(const bf16x8*)&Bs[cur][br * 32 + bs];
    }
#pragma unroll
    for (int mi = 0; mi < 4; ++mi)
#pragma unroll
      for (int ni = 0; ni < 4; ++ni)
        acc[mi][ni] = __builtin_amdgcn_mfma_f32_16x16x32_bf16(af[mi], bfr[ni], acc[mi][ni], 0, 0, 0);

    asm volatile("s_waitcnt vmcnt(0)" ::: "memory");   // A regs + B LDS landed
    if (more) EXPWRITE(cur ^ 1, k0n);
    asm volatile("s_waitcnt lgkmcnt(0)" ::: "memory"); // ds_writes + ds_reads done
    __builtin_amdgcn_s_barrier();
    asm volatile("" ::: "memory");
    cur ^= 1;
  }
#undef ISSUE_A
#undef ISSUE_B
#undef EXPWRITE

  const int rb = mt * 128 + wr * 64;
  const int cb = nt * 128 + wc * 64;
#pragma unroll
  for (int mi = 0; mi < 4; ++mi)
#pragma unroll
    for (int ni = 0; ni < 4; ++ni) {
      const int row0 = rb + mi * 16 + ((lane >> 4) << 2);
      const int col  = cb + ni * 16 + (lane & 15);
#pragma unroll
      for (int j = 0; j < 4; ++j)
        Yb[(long)(row0 + j) * 1024 + col] = f2bf(acc[mi][ni][j]);
    }
}

// ====== per-row max & 1/sumexp over causal length (fp32 S) ======
__global__ __launch_bounds__(256) void rowstats(
    const float* __restrict__ S, float2* __restrict__ st)
{
  const int r = blockIdx.x;              // 0..8191
  const int b = r >> 11, q = r & 2047;
  const float* srow = S + ((long)b * 2048 + q) * 2048;
  const int len = q + 1;
  const int tid = threadIdx.x, lane = tid & 63, wave = tid >> 6;
  const int base = tid * 8;
  __shared__ float red[8];

  float4 x0 = ((const float4*)srow)[tid * 2];
  float4 x1 = ((const float4*)srow)[tid * 2 + 1];
  float vv[8] = {x0.x, x0.y, x0.z, x0.w, x1.x, x1.y, x1.z, x1.w};

  float m = -3.4e38f;
#pragma unroll
  for (int i = 0; i < 8; ++i) if (base + i < len) m = fmaxf(m, vv[i]);
#pragma unroll
  for (int o = 32; o; o >>= 1) m = fmaxf(m, __shfl_xor(m, o));
  if (lane == 0) red[wave] = m;
  __syncthreads();
  m = fmaxf(fmaxf(red[0], red[1]), fmaxf(red[2], red[3]));

  float s = 0.f;
#pragma unroll
  for (int i = 0; i < 8; ++i) if (base + i < len) s += __expf(vv[i] - m);
#pragma unroll
  for (int o = 32; o; o >>= 1) s += __shfl_xor(s, o);
  if (lane == 0) red[4 + wave] = s;
  __syncthreads();
  s = (red[4] + red[5]) + (red[6] + red[7]);

  if (tid == 0) st[r] = (float2){m, 1.f / s};
}

// merged fp32 -> bf16 (RNE)
__global__ __launch_bounds__(256) void convert_all(
    const float* __restrict__ q, const float* __restrict__ k, const float* __restrict__ v,
    const float* __restrict__ wq, const float* __restrict__ wk,
    const float* __restrict__ wv, const float* __restrict__ wp,
    unsigned short* __restrict__ qkv, unsigned short* __restrict__ wb)
{
  const long NQ = 8192L * 1024 / 4;
  const long NW = 1024L * 1024 / 4;
  const int blk = blockIdx.x;
  const float* src; unsigned short* dst; long n; int nb, bb;
  if (blk < 1536) {
    const int s = blk >> 9;
    src = (s == 0) ? q : (s == 1) ? k : v;
    dst = qkv + (long)s * (8192L * 1024);
    n = NQ; nb = 512; bb = blk & 511;
  } else {
    const int s = (blk - 1536) >> 6;
    src = (s == 0) ? wq : (s == 1) ? wk : (s == 2) ? wv : wp;
    dst = wb + (long)s * (1024L * 1024);
    n = NW; nb = 64; bb = (blk - 1536) & 63;
  }
  for (long i = (long)bb * 256 + threadIdx.x; i < n; i += (long)nb * 256) {
    float4 x = ((const float4*)src)[i];
    ushort4 o;
    o.x = f2bf(x.x); o.y = f2bf(x.y); o.z = f2bf(x.z); o.w = f2bf(x.w);
    ((ushort4*)dst)[i] = o;
  }
}

extern "C" void kernel_launch(void* const* d_in, const int* in_sizes, int n_in,
                              void* d_out, int out_size, void* d_ws, size_t ws_size,
                              hipStream_t stream) {
  const float* q  = (const float*)d_in[0];
  const float* k  = (const float*)d_in[1];
  const float* v  = (const float*)d_in[2];
  const float* Wq = (const float*)d_in[3];
  const float* Wk = (const float*)d_in[4];
  const float* Wv = (const float*)d_in[5];
  const float* Wp = (const float*)d_in[6];
  float* out = (float*)d_out;

  const long D  = 1024;
  const long L  = 2048;
  const long ND = 8192 * D;

  char* ws = (char*)d_ws;
  unsigned short* qh    = (unsigned short*)ws;                 // 16 MB (z=0)
  unsigned short* kh    = qh  + ND;                            // 16 MB (z=1)
  unsigned short* vhT   = kh  + ND;                            // 16 MB (z=2, transposed)
  unsigned short* ybf   = vhT + ND;                            // 16 MB
  unsigned short* wbf   = ybf + ND;                            // 8 MB (4 weights)
  float*          S     = (float*)(wbf + 4L * D * D);          // 64 MB fp32
  float2*         stats = (float2*)(S + 4L * L * L);           // 64 KB
  unsigned short* qkvbf = (unsigned short*)S;                  // aliases S (dead before S written)

  // 1) convert inputs + weights to bf16
  convert_all<<<1792, 256, 0, stream>>>(q, k, v, Wq, Wk, Wv, Wp, qkvbf, wbf);

  // 2) merged projections (z=3): qh, kh (mode 0) and vhT (mode 1)
  gemm_bt<<<dim3(512, 3), 256, 0, stream>>>(qkvbf, wbf, qh,
      8192, 1024, 1024, 8, ND, D * D, ND, 3, 0, 1.0f);

  // 3) S = qh * kh^T * 0.125 per batch — triangular tile enumeration (136 valid tiles)
  gemm_bt<<<dim3(136, 4), 256, 0, stream>>>(qh, kh, S,
      2048, 2048, 1024, 16, L * D, L * D, L * L, 2, 1, 0.125f);

  // 4) per-row max + 1/sumexp
  rowstats<<<8192, 256, 0, stream>>>(S, stats);

  // 5) Y = softmax(S) * vh  (fused exp in staging, causal K-limit, XCD-balanced map)
  pv_fused<<<dim3(128, 4), 256, 0, stream>>>(S, stats, vhT, ybf);

  // 6) out = Y * Wproj^T (fp32)
  gemm_bt<<<dim3(512, 1), 256, 0, stream>>>(ybf, wbf + 3 * D * D, out,
      8192, 1024, 1024, 8, 0, 0, 0, 2, 0, 1.0f);
}

// Round 6
// 221.016 us; speedup vs baseline: 1.2665x; 1.2665x over previous
//
#include <hip/hip_runtime.h>
#include <hip/hip_bf16.h>
#include <stdint.h>

typedef __bf16 bf16x8 __attribute__((ext_vector_type(8)));
typedef float  f32x4  __attribute__((ext_vector_type(4)));
typedef unsigned short ushort8v __attribute__((ext_vector_type(8)));

__device__ __forceinline__ unsigned short f2bf(float f) {
  unsigned int u = __float_as_uint(f);
  u += 0x7FFF + ((u >> 16) & 1);          // round-to-nearest-even
  return (unsigned short)(u >> 16);
}

#define GLOAD_LDS(gptr, ldsptr)                                                     \
  __builtin_amdgcn_global_load_lds(                                                 \
      (const __attribute__((address_space(1))) unsigned int*)(gptr),                \
      (__attribute__((address_space(3))) unsigned int*)(ldsptr), 16, 0, 0)

#define BM 128
#define BN 128
#define BK 32

// ============ 128x128 3-buf GEMM: C = A[M,K] * B[N,K]^T (bf16 in) ============
// mode 0: C bf16 [M,N]; mode 1: C bf16 transposed-per-batch (vhT); mode 2: fp32*scale
// mode 3: merged projections (z<2 -> mode 0, z==2 -> mode 1)
// tilemap 0: m204 XCD chunk swizzle, mt = wg/ntiles (uniform-work grids)
// tilemap 1: triangular decode -> (mt,nt), nt<=mt (causal S; RR-balanced)
// tilemap 2: paired causal map mt={c,15-c}, nt=orig>>4, + K-limit (PV)
__global__ __launch_bounds__(256, 3) void gemm_bt(
    const unsigned short* __restrict__ A,
    const unsigned short* __restrict__ B,
    void* __restrict__ C,
    int M, int N, int K, int ntiles,
    long sAz, long sBz, long sCz,
    int mode, int tilemap, float scale)
{
  int mt, nt;
  const int orig = blockIdx.x;
  if (tilemap == 0) {
    const int nwg = gridDim.x;
    const int qq = nwg >> 3, rr = nwg & 7, xc = orig & 7, oo = orig >> 3;
    const int wg = (xc < rr ? xc * (qq + 1) : rr * (qq + 1) + (xc - rr) * qq) + oo;
    mt = wg / ntiles; nt = wg % ntiles;
  } else if (tilemap == 1) {
    mt = (int)((sqrtf(8.f * orig + 1.f) - 1.f) * 0.5f);
    int base = mt * (mt + 1) / 2;
    if (orig < base) { mt--; base = mt * (mt + 1) / 2; }
    else if (orig >= base + mt + 1) { mt++; base = mt * (mt + 1) / 2; }
    nt = orig - base;
  } else {
    const int c = orig & 15;
    mt = (c & 8) ? (15 - (c & 7)) : c;
    nt = orig >> 4;
  }
  const int z = blockIdx.y;
  const int emode = (mode == 3) ? (z == 2 ? 1 : 0) : mode;

  A += sAz * (long)z;
  B += sBz * (long)z;

  __shared__ __align__(16) unsigned short As[3][BM * BK];
  __shared__ __align__(16) unsigned short Bs[3][BN * BK];

  const int tid  = threadIdx.x;
  const int wave = tid >> 6;
  const int lane = tid & 63;
  const int wr = wave >> 1, wc = wave & 1;

  f32x4 acc[4][4];
#pragma unroll
  for (int i = 0; i < 4; ++i)
#pragma unroll
    for (int j = 0; j < 4; ++j) acc[i][j] = (f32x4){0.f, 0.f, 0.f, 0.f};

  int kiters = K / BK;
  if (tilemap == 2) { const int kl = (mt + 1) * (BM / BK); if (kl < kiters) kiters = kl; }

  // staging: XOR-swizzled global source, linear LDS dest (rule 21)
  const int r0 = tid >> 2, s0 = tid & 3;
  const int c0 = ((s0 ^ ((r0 >> 1) & 3)) << 3);
  const int r1 = r0 + 64;
  const int c1 = ((s0 ^ ((r1 >> 1) & 3)) << 3);
  const long aoff0 = (long)(mt * BM + r0) * K + c0;
  const long aoff1 = (long)(mt * BM + r1) * K + c1;
  const long boff0 = (long)(nt * BN + r0) * K + c0;
  const long boff1 = (long)(nt * BN + r1) * K + c1;
  const unsigned ldsw = wave * 1024;

#define STAGE(bi, k0)                                                     \
  do {                                                                    \
    GLOAD_LDS(A + aoff0 + (k0), (char*)&As[bi][0]    + ldsw);             \
    GLOAD_LDS(A + aoff1 + (k0), (char*)&As[bi][2048] + ldsw);             \
    GLOAD_LDS(B + boff0 + (k0), (char*)&Bs[bi][0]    + ldsw);             \
    GLOAD_LDS(B + boff1 + (k0), (char*)&Bs[bi][2048] + ldsw);             \
  } while (0)

  STAGE(0, 0);
  if (kiters > 1) STAGE(1, BK);

  int cur = 0;
  for (int kt = 0; kt < kiters; ++kt) {
    const int rem = kiters - 1 - kt;
    if (rem >= 2) {
      int sb = cur + 2; if (sb >= 3) sb -= 3;
      STAGE(sb, (kt + 2) * BK);
      asm volatile("s_waitcnt vmcnt(8)" ::: "memory");
    } else if (rem == 1) {
      asm volatile("s_waitcnt vmcnt(4)" ::: "memory");
    } else {
      asm volatile("s_waitcnt vmcnt(0)" ::: "memory");
    }
    __builtin_amdgcn_s_barrier();
    asm volatile("" ::: "memory");

    bf16x8 af[4], bfr[4];
#pragma unroll
    for (int i = 0; i < 4; ++i) {
      const int ar = wr * 64 + i * 16 + (lane & 15);
      const int as = ((lane >> 4) ^ ((ar >> 1) & 3)) << 3;
      af[i] = *(const bf16x8*)&As[cur][ar * BK + as];
      const int br = wc * 64 + i * 16 + (lane & 15);
      const int bs = ((lane >> 4) ^ ((br >> 1) & 3)) << 3;
      bfr[i] = *(const bf16x8*)&Bs[cur][br * BK + bs];
    }
#pragma unroll
    for (int mi = 0; mi < 4; ++mi)
#pragma unroll
      for (int ni = 0; ni < 4; ++ni)
        acc[mi][ni] = __builtin_amdgcn_mfma_f32_16x16x32_bf16(af[mi], bfr[ni], acc[mi][ni], 0, 0, 0);

    asm volatile("" ::: "memory");
    __builtin_amdgcn_s_barrier();
    cur = (cur == 2) ? 0 : cur + 1;
  }
#undef STAGE

  const int rb = mt * BM + wr * 64;
  const int cb = nt * BN + wc * 64;

  if (emode == 0) {
    unsigned short* Cb = (unsigned short*)C + sCz * (long)z;
#pragma unroll
    for (int mi = 0; mi < 4; ++mi)
#pragma unroll
      for (int ni = 0; ni < 4; ++ni) {
        const int row0 = rb + mi * 16 + ((lane >> 4) << 2);
        const int col  = cb + ni * 16 + (lane & 15);
#pragma unroll
        for (int j = 0; j < 4; ++j)
          Cb[(long)(row0 + j) * N + col] = f2bf(acc[mi][ni][j]);
      }
  } else if (emode == 1) {
    unsigned short* Cb = (unsigned short*)C + sCz * (long)z;
#pragma unroll
    for (int mi = 0; mi < 4; ++mi)
#pragma unroll
      for (int ni = 0; ni < 4; ++ni) {
        const int row0 = rb + mi * 16 + ((lane >> 4) << 2);
        const int col  = cb + ni * 16 + (lane & 15);
#pragma unroll
        for (int j = 0; j < 4; ++j) {
          const int row = row0 + j;
          const int b = row >> 11, l = row & 2047;
          Cb[((long)b * N + col) * 2048 + l] = f2bf(acc[mi][ni][j]);
        }
      }
  } else {
    float* Cf = (float*)C + sCz * (long)z;
#pragma unroll
    for (int mi = 0; mi < 4; ++mi)
#pragma unroll
      for (int ni = 0; ni < 4; ++ni) {
        const int row0 = rb + mi * 16 + ((lane >> 4) << 2);
        const int col  = cb + ni * 16 + (lane & 15);
#pragma unroll
        for (int j = 0; j < 4; ++j)
          Cf[(long)(row0 + j) * N + col] = acc[mi][ni][j] * scale;
      }
  }
}

// single-pass causal row softmax, bounded at the 128-tile ceiling of the row.
// S fp32 [B,L,L] -> P bf16; cols [len, lenceil) get zeros; cols >= lenceil never
// read by PV (K-limit) so left untouched.
__global__ __launch_bounds__(256) void softmax_causal(
    const float* __restrict__ S, unsigned short* __restrict__ P, int L)
{
  const int r = blockIdx.x;              // 0..B*L-1
  const int b = r >> 11, q = r & 2047;
  const float* srow = S + ((long)b * L + q) * L;
  unsigned short* prow = P + ((long)b * L + q) * L;
  const int len = q + 1;
  const int lenceil = ((q >> 7) + 1) << 7;   // PV reads exactly this many cols
  const int tid = threadIdx.x, lane = tid & 63, wave = tid >> 6;
  const int base = tid * 8;
  const bool active = base < lenceil;
  __shared__ float red[8];

  float vv[8];
#pragma unroll
  for (int i = 0; i < 8; ++i) vv[i] = -3.4e38f;
  if (active) {
    float4 x0 = ((const float4*)srow)[tid * 2];
    float4 x1 = ((const float4*)srow)[tid * 2 + 1];
    vv[0] = x0.x; vv[1] = x0.y; vv[2] = x0.z; vv[3] = x0.w;
    vv[4] = x1.x; vv[5] = x1.y; vv[6] = x1.z; vv[7] = x1.w;
  }

  float m = -3.4e38f;
#pragma unroll
  for (int i = 0; i < 8; ++i) if (base + i < len) m = fmaxf(m, vv[i]);
#pragma unroll
  for (int o = 32; o; o >>= 1) m = fmaxf(m, __shfl_xor(m, o));
  if (lane == 0) red[wave] = m;
  __syncthreads();
  m = fmaxf(fmaxf(red[0], red[1]), fmaxf(red[2], red[3]));

  float p[8], s = 0.f;
#pragma unroll
  for (int i = 0; i < 8; ++i) {
    p[i] = (base + i < len) ? __expf(vv[i] - m) : 0.f;
    s += p[i];
  }
#pragma unroll
  for (int o = 32; o; o >>= 1) s += __shfl_xor(s, o);
  if (lane == 0) red[4 + wave] = s;
  __syncthreads();
  s = (red[4] + red[5]) + (red[6] + red[7]);
  const float inv = 1.f / s;

  if (active) {
    ushort8v o16;
#pragma unroll
    for (int i = 0; i < 8; ++i) o16[i] = f2bf(p[i] * inv);
    *(ushort8v*)(prow + base) = o16;
  }
}

// merged fp32 -> bf16 (RNE)
__global__ __launch_bounds__(256) void convert_all(
    const float* __restrict__ q, const float* __restrict__ k, const float* __restrict__ v,
    const float* __restrict__ wq, const float* __restrict__ wk,
    const float* __restrict__ wv, const float* __restrict__ wp,
    unsigned short* __restrict__ qkv, unsigned short* __restrict__ wb)
{
  const long NQ = 8192L * 1024 / 4;
  const long NW = 1024L * 1024 / 4;
  const int blk = blockIdx.x;
  const float* src; unsigned short* dst; long n; int nb, bb;
  if (blk < 1536) {
    const int s = blk >> 9;
    src = (s == 0) ? q : (s == 1) ? k : v;
    dst = qkv + (long)s * (8192L * 1024);
    n = NQ; nb = 512; bb = blk & 511;
  } else {
    const int s = (blk - 1536) >> 6;
    src = (s == 0) ? wq : (s == 1) ? wk : (s == 2) ? wv : wp;
    dst = wb + (long)s * (1024L * 1024);
    n = NW; nb = 64; bb = (blk - 1536) & 63;
  }
  for (long i = (long)bb * 256 + threadIdx.x; i < n; i += (long)nb * 256) {
    float4 x = ((const float4*)src)[i];
    ushort4 o;
    o.x = f2bf(x.x); o.y = f2bf(x.y); o.z = f2bf(x.z); o.w = f2bf(x.w);
    ((ushort4*)dst)[i] = o;
  }
}

extern "C" void kernel_launch(void* const* d_in, const int* in_sizes, int n_in,
                              void* d_out, int out_size, void* d_ws, size_t ws_size,
                              hipStream_t stream) {
  const float* q  = (const float*)d_in[0];
  const float* k  = (const float*)d_in[1];
  const float* v  = (const float*)d_in[2];
  const float* Wq = (const float*)d_in[3];
  const float* Wk = (const float*)d_in[4];
  const float* Wv = (const float*)d_in[5];
  const float* Wp = (const float*)d_in[6];
  float* out = (float*)d_out;

  const long D  = 1024;
  const long L  = 2048;
  const long ND = 8192 * D;
  const long NS = 4L * L * L;

  char* ws = (char*)d_ws;
  unsigned short* qh    = (unsigned short*)ws;                 // 16 MB (z=0)
  unsigned short* kh    = qh  + ND;                            // 16 MB (z=1)
  unsigned short* vhT   = kh  + ND;                            // 16 MB (z=2, transposed)
  unsigned short* P     = vhT + ND;                            // 32 MB
  unsigned short* ybf   = P   + NS;                            // 16 MB
  unsigned short* wbf   = ybf + ND;                            // 8 MB (4 weights)
  float*          S     = (float*)(wbf + 4L * D * D);          // 64 MB fp32
  unsigned short* qkvbf = (unsigned short*)S;                  // aliases S (dead before S written)

  // 1) convert inputs + weights to bf16
  convert_all<<<1792, 256, 0, stream>>>(q, k, v, Wq, Wk, Wv, Wp, qkvbf, wbf);

  // 2) merged projections (z=3): qh, kh (mode 0) and vhT (mode 1)
  gemm_bt<<<dim3(512, 3), 256, 0, stream>>>(qkvbf, wbf, qh,
      8192, 1024, 1024, 8, ND, D * D, ND, 3, 0, 1.0f);

  // 3) S = qh * kh^T * 0.125 per batch — triangular tile enumeration (136 tiles)
  gemm_bt<<<dim3(136, 4), 256, 0, stream>>>(qh, kh, S,
      2048, 2048, 1024, 16, L * D, L * D, L * L, 2, 1, 0.125f);

  // 4) causal softmax -> P (bounded at 128-tile ceiling)
  softmax_causal<<<8192, 256, 0, stream>>>(S, P, 2048);

  // 5) Y = P * vh (paired XCD map + K-limit)
  gemm_bt<<<dim3(128, 4), 256, 0, stream>>>(P, vhT, ybf,
      2048, 1024, 2048, 8, L * L, D * L, L * D, 0, 2, 1.0f);

  // 6) out = Y * Wproj^T (fp32)
  gemm_bt<<<dim3(512, 1), 256, 0, stream>>>(ybf, wbf + 3 * D * D, out,
      8192, 1024, 1024, 8, 0, 0, 0, 2, 0, 1.0f);
}